// Round 7
// baseline (29460.599 us; speedup 1.0000x reference)
//
#include <hip/hip_runtime.h>
#include <math.h>

#define B_ 64
#define T_ 1000
#define IN_ 80
#define H_ 512
#define V_ 1000
#define S_ 100

// ---------------------------------------------------------------------------
// split-phase group barrier.
// bar_arrive: MUST be preceded by __syncthreads() (drains all waves' global
// stores to L2 via vmcnt(0)). The RELEASE fetch_add emits waitcnt+wbl2
// first -> the whole block's hT stores (same physical L2) reach L3 before the
// counter bump is visible.
// bar_wait: RELAXED polls (an ACQUIRE poll would buffer_inv the XCD L2 every
// iteration, evicting the L2-resident W slice!); single __threadfence (wb+inv)
// after success, then syncthreads, so all threads' subsequent hT reads miss
// stale L2.
// ---------------------------------------------------------------------------
__device__ __forceinline__ void bar_arrive(unsigned* ctr) {
  if (threadIdx.x == 0)
    __hip_atomic_fetch_add(ctr, 1u, __ATOMIC_RELEASE, __HIP_MEMORY_SCOPE_AGENT);
}
__device__ __forceinline__ void bar_wait(unsigned* ctr, unsigned target) {
  if (threadIdx.x == 0) {
    long guard = 0;
    while (__hip_atomic_load(ctr, __ATOMIC_RELAXED, __HIP_MEMORY_SCOPE_AGENT) < target) {
      __builtin_amdgcn_s_sleep(2);
      if (++guard > 20000) break;  // fast-fail: wrong-but-finite instead of hang
    }
    __threadfence();  // acquire: wb+inv local L2 once before re-reading hT
  }
  __syncthreads();
}

__device__ __forceinline__ float sigm(float x) { return 1.f / (1.f + __expf(-x)); }

// ---------------------------------------------------------------------------
// sentinel: ws_size too small -> readable failure instead of memory fault
// ---------------------------------------------------------------------------
__global__ void k_sentinel(float* __restrict__ out, float required_mb) {
  if (threadIdx.x == 0 && blockIdx.x == 0) out[0] = required_mb;
}

// ---------------------------------------------------------------------------
// K0: transpose x[B][T][IN] -> xT[T][IN][B]
// ---------------------------------------------------------------------------
__global__ void k_transpose_x(const float* __restrict__ x, float* __restrict__ xT) {
  __shared__ float tile[64][81];
  const int t = blockIdx.x;
  for (int idx = threadIdx.x; idx < 64 * IN_; idx += 256) {
    const int b = idx / IN_, k = idx % IN_;
    tile[b][k] = x[((size_t)b * T_ + t) * IN_ + k];
  }
  __syncthreads();
  for (int idx = threadIdx.x; idx < IN_ * 64; idx += 256) {
    const int k = idx >> 6, b = idx & 63;
    xT[((size_t)t * IN_ + k) * 64 + b] = tile[b][k];
  }
}

// ---------------------------------------------------------------------------
// K0b: W_sum = W_ih_d + W_hh_d  (decoder steps >=1 have x input == h)
// ---------------------------------------------------------------------------
__global__ void k_wsum(const float* __restrict__ a, const float* __restrict__ b,
                       float* __restrict__ o, int n) {
  const int i = blockIdx.x * 256 + threadIdx.x;
  if (i < n) o[i] = a[i] + b[i];
}

// ---------------------------------------------------------------------------
// Encoder: persistent kernel (regular launch; 256 blocks on 256 CUs with
// __launch_bounds__(256,1) guarantees co-residency), 1000 sequential steps.
// 256 blocks = 4 b-groups (16 batch rows) x 64 n-blocks (8 j-cols x 4 gates).
//
// XCD-aware remap: ng = (bid&7)*8 + ((bid>>3)&7) puts n-groups [8x,8x+8) on
// XCD x for all b-groups: per-XCD W working set 606 KB << 4 MB L2.
//
// Split-phase barrier: arrive right after hT write; enc_out write + next
// x-stage overlap other blocks' arrival; wait at top of next iteration.
//
// Staging is float4 along the contiguous b-dim of hT/xT (G13: hipcc won't
// auto-vectorize): 8 dwordx4 + 32 ds_write per thread instead of 32+32
// scalar; LDS write banks (16*bb4+k)%32 -> worst 2-way (free).
// ---------------------------------------------------------------------------
__launch_bounds__(256, 1)
__global__ void k_encoder(const float* __restrict__ xT,
                          const float* __restrict__ W_ih_e,   // [2048][80]
                          const float* __restrict__ W_hh_e,   // [2048][512]
                          const float* __restrict__ b_ih_e,
                          const float* __restrict__ b_hh_e,
                          float* __restrict__ enc_out,        // [B][T][H]
                          float* __restrict__ hT,             // [2][512][64]
                          float* __restrict__ c_buf,          // [B][H]
                          unsigned* __restrict__ bar) {
  const int tid = threadIdx.x;
  const int bid = blockIdx.x;
  const int gb  = bid >> 6;                          // b-group 0..3 (barrier group)
  const int ng  = (bid & 7) * 8 + ((bid >> 3) & 7);  // n-group 0..63, XCD-sliced
  const int bl  = tid & 15;          // local batch row 0..15
  const int rq  = tid >> 4;          // 0..15
  const int b_glob = gb * 16 + bl;
  const int jj  = rq & 7;
  const int gh  = rq >> 3;               // 0: gate i, 1: gate f
  const int j   = ng * 8 + jj;
  const int n1  = gh * 512 + j;          // i or f row
  const int n2  = n1 + 1024;             // g or o row

  __shared__ float hx[16][596];   // [b][k]: 80 x-part + 512 h-part (pitch 596)
  __shared__ float gbuf[16][33];  // padded: conflict-free gate exchange

  const float bias1 = b_ih_e[n1] + b_hh_e[n1];
  const float bias2 = b_ih_e[n2] + b_hh_e[n2];
  const float4* Wx1 = (const float4*)(W_ih_e + (size_t)n1 * IN_);
  const float4* Wx2 = (const float4*)(W_ih_e + (size_t)n2 * IN_);
  const float4* Wh1 = (const float4*)(W_hh_e + (size_t)n1 * H_);
  const float4* Wh2 = (const float4*)(W_hh_e + (size_t)n2 * H_);

  float c = 0.f;
  unsigned wait_target = 0;

  // prologue: stage x-part for t=0 (320 float4 = 16 rows x 80 k)
  for (int idx = tid; idx < 320; idx += 256) {
    const int k = idx >> 2, bb4 = (idx & 3) * 4;
    const float4 v = *(const float4*)&xT[(size_t)0 * (IN_ * 64) + k * 64 + gb * 16 + bb4];
    hx[bb4 + 0][k] = v.x; hx[bb4 + 1][k] = v.y;
    hx[bb4 + 2][k] = v.z; hx[bb4 + 3][k] = v.w;
  }

  for (int t = 0; t < T_; ++t) {
    bar_wait(&bar[gb], wait_target);   // h_t visible (t=0: trivial) + syncthreads
    const float* hsrc = hT + (size_t)(t & 1) * H_ * 64;
    // stage h slice [16][512]: 2048 float4, 8 per thread
    #pragma unroll
    for (int l = 0; l < 8; ++l) {
      const int idx = tid + l * 256;
      const int k = idx >> 2, bb4 = (idx & 3) * 4;
      const float4 v = *(const float4*)&hsrc[k * 64 + gb * 16 + bb4];
      hx[bb4 + 0][IN_ + k] = v.x;
      hx[bb4 + 1][IN_ + k] = v.y;
      hx[bb4 + 2][IN_ + k] = v.z;
      hx[bb4 + 3][IN_ + k] = v.w;
    }
    __syncthreads();

    float acc1 = bias1, acc2 = bias2;
    const float4* hx4 = (const float4*)(&hx[bl][0]);
    #pragma unroll 10
    for (int i = 0; i < IN_ / 4; ++i) {
      const float4 h4 = hx4[i];
      const float4 w1 = Wx1[i], w2 = Wx2[i];
      acc1 = fmaf(h4.x, w1.x, acc1); acc1 = fmaf(h4.y, w1.y, acc1);
      acc1 = fmaf(h4.z, w1.z, acc1); acc1 = fmaf(h4.w, w1.w, acc1);
      acc2 = fmaf(h4.x, w2.x, acc2); acc2 = fmaf(h4.y, w2.y, acc2);
      acc2 = fmaf(h4.z, w2.z, acc2); acc2 = fmaf(h4.w, w2.w, acc2);
    }
    const float4* hh4 = (const float4*)(&hx[bl][IN_]);
    #pragma unroll 16
    for (int i = 0; i < H_ / 4; ++i) {
      const float4 h4 = hh4[i];
      const float4 w1 = Wh1[i], w2 = Wh2[i];
      acc1 = fmaf(h4.x, w1.x, acc1); acc1 = fmaf(h4.y, w1.y, acc1);
      acc1 = fmaf(h4.z, w1.z, acc1); acc1 = fmaf(h4.w, w1.w, acc1);
      acc2 = fmaf(h4.x, w2.x, acc2); acc2 = fmaf(h4.y, w2.y, acc2);
      acc2 = fmaf(h4.z, w2.z, acc2); acc2 = fmaf(h4.w, w2.w, acc2);
    }

    gbuf[bl][rq] = acc1;       // rq 0..7: gate i, 8..15: gate f
    __syncthreads();
    gbuf[bl][rq + 16] = acc2;  // 16..23: gate g, 24..31: gate o
    __syncthreads();

    float hval = 0.f;
    if (rq < 8) {
      const float gi = gbuf[bl][jj];
      const float gf = gbuf[bl][8 + jj];
      const float gg = gbuf[bl][16 + jj];
      const float go = gbuf[bl][24 + jj];
      c = sigm(gf) * c + sigm(gi) * tanhf(gg);
      hval = sigm(go) * tanhf(c);
      hT[(size_t)((t + 1) & 1) * H_ * 64 + j * 64 + b_glob] = hval;
    }
    __syncthreads();                   // hT writes drained block-wide (vmcnt 0)
    bar_arrive(&bar[gb]);
    wait_target += 64;

    // ---- overlap region: runs under other blocks' arrival latency ----
    if (rq < 8) enc_out[((size_t)b_glob * T_ + t) * H_ + j] = hval;
    if (t + 1 < T_) {                  // stage x-part for t+1 (hx free: compute done)
      for (int idx = tid; idx < 320; idx += 256) {
        const int k = idx >> 2, bb4 = (idx & 3) * 4;
        const float4 v =
            *(const float4*)&xT[(size_t)(t + 1) * (IN_ * 64) + k * 64 + gb * 16 + bb4];
        hx[bb4 + 0][k] = v.x; hx[bb4 + 1][k] = v.y;
        hx[bb4 + 2][k] = v.z; hx[bb4 + 3][k] = v.w;
      }
    }
  }
  if (rq < 8) c_buf[(size_t)b_glob * H_ + j] = c;
}

// ---------------------------------------------------------------------------
// Decoder LSTM: 100 sequential steps. dec_in == previous h (step 0: x = 0),
// so gates = h @ (W_ih_d + W_hh_d)^T + b   (step 0: h @ W_hh_d^T + b).
// Attention does NOT feed back -> done later as parallel GEMMs.
// Same XCD-sliced remap + split-phase barrier + float4 staging as encoder.
// ---------------------------------------------------------------------------
__launch_bounds__(256, 1)
__global__ void k_decoder(const float* __restrict__ W_hh_d,  // [2048][512]
                          const float* __restrict__ W_sum,   // [2048][512]
                          const float* __restrict__ b_ih_d,
                          const float* __restrict__ b_hh_d,
                          const float* __restrict__ c_in,    // [B][H]
                          float* __restrict__ Hd,            // [B][S][H]
                          float* __restrict__ hT,            // [2][512][64]
                          unsigned* __restrict__ bar) {
  const int tid = threadIdx.x;
  const int bid = blockIdx.x;
  const int gb  = bid >> 6;
  const int ng  = (bid & 7) * 8 + ((bid >> 3) & 7);
  const int bl  = tid & 15;
  const int rq  = tid >> 4;
  const int b_glob = gb * 16 + bl;
  const int jj  = rq & 7;
  const int gh  = rq >> 3;
  const int j   = ng * 8 + jj;
  const int n1  = gh * 512 + j;
  const int n2  = n1 + 1024;

  __shared__ float hb[16][516];
  __shared__ float gbuf[16][33];

  const float bias1 = b_ih_d[n1] + b_hh_d[n1];
  const float bias2 = b_ih_d[n2] + b_hh_d[n2];

  float c = (rq < 8) ? c_in[(size_t)b_glob * H_ + j] : 0.f;
  unsigned wait_target = 0;

  for (int s = 0; s < S_; ++s) {
    bar_wait(&bar[8 + gb], wait_target);
    const float* hsrc = hT + (size_t)(s & 1) * H_ * 64;
    #pragma unroll
    for (int l = 0; l < 8; ++l) {
      const int idx = tid + l * 256;
      const int k = idx >> 2, bb4 = (idx & 3) * 4;
      const float4 v = *(const float4*)&hsrc[k * 64 + gb * 16 + bb4];
      hb[bb4 + 0][k] = v.x; hb[bb4 + 1][k] = v.y;
      hb[bb4 + 2][k] = v.z; hb[bb4 + 3][k] = v.w;
    }
    __syncthreads();

    const float* Wbase = (s == 0) ? W_hh_d : W_sum;
    const float4* W1 = (const float4*)(Wbase + (size_t)n1 * H_);
    const float4* W2 = (const float4*)(Wbase + (size_t)n2 * H_);
    float acc1 = bias1, acc2 = bias2;
    const float4* h4p = (const float4*)(&hb[bl][0]);
    #pragma unroll 16
    for (int i = 0; i < H_ / 4; ++i) {
      const float4 h4 = h4p[i];
      const float4 w1 = W1[i], w2 = W2[i];
      acc1 = fmaf(h4.x, w1.x, acc1); acc1 = fmaf(h4.y, w1.y, acc1);
      acc1 = fmaf(h4.z, w1.z, acc1); acc1 = fmaf(h4.w, w1.w, acc1);
      acc2 = fmaf(h4.x, w2.x, acc2); acc2 = fmaf(h4.y, w2.y, acc2);
      acc2 = fmaf(h4.z, w2.z, acc2); acc2 = fmaf(h4.w, w2.w, acc2);
    }

    gbuf[bl][rq] = acc1;
    __syncthreads();
    gbuf[bl][rq + 16] = acc2;
    __syncthreads();

    float hval = 0.f;
    if (rq < 8) {
      const float gi = gbuf[bl][jj];
      const float gf = gbuf[bl][8 + jj];
      const float gg = gbuf[bl][16 + jj];
      const float go = gbuf[bl][24 + jj];
      c = sigm(gf) * c + sigm(gi) * tanhf(gg);
      hval = sigm(go) * tanhf(c);
      hT[(size_t)((s + 1) & 1) * H_ * 64 + j * 64 + b_glob] = hval;
    }
    __syncthreads();
    bar_arrive(&bar[8 + gb]);
    wait_target += 64;
    // overlap: Hd is not read inside the loop
    if (rq < 8) Hd[((size_t)b_glob * S_ + s) * H_ + j] = hval;
  }
}

// ---------------------------------------------------------------------------
// Tiled GEMM: C[M][N] = A[M][K] @ B (+bias). 128x128 tile, kc=16, 8x8 micro.
// MODE 0: B=[N][K] (NT), batched over z      -> scores
// MODE 1: B=[K][N] (NN), batched over z      -> ctx
// MODE 2: NT flat, A=concat(ctx,Hd), +bias   -> attn_applied
// MODE 3: NT flat, +bias                     -> logits
// ---------------------------------------------------------------------------
template <int MODE>
__launch_bounds__(256, 2)
__global__ void k_gemm(const float* __restrict__ A, const float* __restrict__ A2,
                       const float* __restrict__ Bm, const float* __restrict__ bias,
                       float* __restrict__ C, int M, int N, int K,
                       long sA, long sB, long sC) {
  constexpr bool NN = (MODE == 1);
  constexpr bool CONCAT = (MODE == 2);
  constexpr bool HASBIAS = (MODE >= 2);
  __shared__ float As[16][132];  // [k][m]
  __shared__ float Bs[16][132];  // [k][n]
  const int bz = blockIdx.z;
  const float* Ab = A + (long)bz * sA;
  const float* Bb = Bm + (long)bz * sB;
  float* Cb = C + (long)bz * sC;
  const int m0 = blockIdx.y * 128, n0 = blockIdx.x * 128;
  const int tid = threadIdx.x;
  const int tx = tid & 15, ty = tid >> 4;
  float acc[8][8] = {};

  for (int kc = 0; kc < K; kc += 16) {
    // A tile: 128m x 16k -> As[k][m]
    #pragma unroll
    for (int l = 0; l < 8; ++l) {
      const int idx = tid + l * 256;
      const int m = idx >> 4, k = idx & 15;
      const int mm = m0 + m, kk = kc + k;
      float v = 0.f;
      if (mm < M && kk < K) {
        if (CONCAT) v = (kk < H_) ? Ab[(long)mm * H_ + kk] : A2[(long)mm * H_ + (kk - H_)];
        else        v = Ab[(long)mm * K + kk];
      }
      As[k][m] = v;
    }
    // B tile: 128n x 16k -> Bs[k][n]
    #pragma unroll
    for (int l = 0; l < 8; ++l) {
      const int idx = tid + l * 256;
      int n, k;
      if (NN) { n = idx & 127; k = idx >> 7; }
      else    { k = idx & 15;  n = idx >> 4; }
      const int nn = n0 + n, kk = kc + k;
      float v = 0.f;
      if (nn < N && kk < K)
        v = NN ? Bb[(long)kk * N + nn] : Bb[(long)nn * K + kk];
      Bs[k][n] = v;
    }
    __syncthreads();

    #pragma unroll 8
    for (int k = 0; k < 16; ++k) {
      const float4 a0 = *(const float4*)&As[k][ty * 4];
      const float4 a1 = *(const float4*)&As[k][ty * 4 + 64];
      const float4 b0 = *(const float4*)&Bs[k][tx * 4];
      const float4 b1 = *(const float4*)&Bs[k][tx * 4 + 64];
      const float a[8] = {a0.x, a0.y, a0.z, a0.w, a1.x, a1.y, a1.z, a1.w};
      const float b[8] = {b0.x, b0.y, b0.z, b0.w, b1.x, b1.y, b1.z, b1.w};
      #pragma unroll
      for (int i = 0; i < 8; ++i)
        #pragma unroll
        for (int jy = 0; jy < 8; ++jy)
          acc[i][jy] = fmaf(a[i], b[jy], acc[i][jy]);
    }
    __syncthreads();
  }

  #pragma unroll
  for (int i = 0; i < 8; ++i) {
    const int m = m0 + ty * 4 + (i & 3) + (i >> 2) * 64;
    if (m >= M) continue;
    #pragma unroll
    for (int jy = 0; jy < 8; ++jy) {
      const int n = n0 + tx * 4 + (jy & 3) + (jy >> 2) * 64;
      if (n < N) {
        float v = acc[i][jy];
        if (HASBIAS) v += bias[n];
        Cb[(long)m * N + n] = v;
      }
    }
  }
}

// ---------------------------------------------------------------------------
// Softmax over T for each (b,s) row of scores[B][S][T], in place.
// Wave __shfl_xor reduce + 8-float LDS combine (2 syncthreads total).
// ---------------------------------------------------------------------------
__global__ void k_softmax(float* __restrict__ scores) {
  __shared__ float red[8];
  float* row = scores + (size_t)blockIdx.x * T_;
  const int tid = threadIdx.x;
  const int lane = tid & 63, wv = tid >> 6;
  float r[4];
  float mx = -1e30f;
  #pragma unroll
  for (int i = 0; i < 4; ++i) {
    const int idx = tid + i * 256;
    r[i] = (idx < T_) ? row[idx] : -1e30f;
    mx = fmaxf(mx, r[i]);
  }
  #pragma unroll
  for (int off = 32; off > 0; off >>= 1) mx = fmaxf(mx, __shfl_xor(mx, off, 64));
  if (lane == 0) red[wv] = mx;
  __syncthreads();
  mx = fmaxf(fmaxf(red[0], red[1]), fmaxf(red[2], red[3]));
  float sum = 0.f;
  #pragma unroll
  for (int i = 0; i < 4; ++i) {
    const int idx = tid + i * 256;
    r[i] = (idx < T_) ? __expf(r[i] - mx) : 0.f;
    sum += r[i];
  }
  #pragma unroll
  for (int off = 32; off > 0; off >>= 1) sum += __shfl_xor(sum, off, 64);
  if (lane == 0) red[4 + wv] = sum;
  __syncthreads();
  const float inv = 1.f / (red[4] + red[5] + red[6] + red[7]);
  #pragma unroll
  for (int i = 0; i < 4; ++i) {
    const int idx = tid + i * 256;
    if (idx < T_) row[idx] = r[i] * inv;
  }
}

// ---------------------------------------------------------------------------
// launcher
// ---------------------------------------------------------------------------
extern "C" void kernel_launch(void* const* d_in, const int* in_sizes, int n_in,
                              void* d_out, int out_size, void* d_ws, size_t ws_size,
                              hipStream_t stream) {
  const float* x      = (const float*)d_in[0];
  const float* W_ih_e = (const float*)d_in[1];
  const float* W_hh_e = (const float*)d_in[2];
  const float* b_ih_e = (const float*)d_in[3];
  const float* b_hh_e = (const float*)d_in[4];
  const float* W_ih_d = (const float*)d_in[5];
  const float* W_hh_d = (const float*)d_in[6];
  const float* b_ih_d = (const float*)d_in[7];
  const float* b_hh_d = (const float*)d_in[8];
  const float* W_attn = (const float*)d_in[9];
  const float* b_attn = (const float*)d_in[10];
  const float* W_fc   = (const float*)d_in[11];
  const float* b_fc   = (const float*)d_in[12];
  // d_in[13] = max_len (always 100, compile-time S_)

  // ---- workspace layout (floats) ----
  // bar        : 64 unsigned  (256 B)
  // sh         : 5,120,000    (xT [T][IN][64]; later reused for attn_applied)
  // enc_out    : 32,768,000   ([B][T][H])
  // hT         : 65,536       ([2][512][64])
  // c_buf      : 32,768       ([B][H])
  // Hd         : 3,276,800    ([B][S][H])
  // ctx        : 3,276,800    ([B][S][H])
  // W_sum      : 1,048,576    ([2048][512])
  // scores     : aliased into d_out (exactly out_size = 6,400,000 floats)
  const size_t need_fl = 5120000ull + 32768000ull + 65536ull + 32768ull +
                         3276800ull + 3276800ull + 1048576ull;
  const size_t required = 256ull + need_fl * 4ull;
  if (ws_size < required) {
    // readable failure: d_out[0] = required MB (instead of an OOB fault)
    k_sentinel<<<1, 64, 0, stream>>>((float*)d_out, (float)(required >> 20));
    return;
  }

  unsigned* bar  = (unsigned*)d_ws;
  float* sh      = (float*)((char*)d_ws + 256);
  float* enc_out = sh + 5120000;
  float* hT      = enc_out + 32768000;
  float* c_buf   = hT + 65536;
  float* Hd      = c_buf + 32768;
  float* ctx     = Hd + 3276800;
  float* W_sum   = ctx + 3276800;
  float* scores  = (float*)d_out;   // [B][S][T] == out_size, dead before logits
  float* attn    = sh;              // xT dead once encoder finishes
  float* logits  = (float*)d_out;

  hipMemsetAsync(d_ws, 0, 256, stream);                        // barrier counters
  hipMemsetAsync(hT, 0, 2 * H_ * 64 * sizeof(float), stream);  // h0 = 0

  k_transpose_x<<<T_, 256, 0, stream>>>(x, sh);
  k_wsum<<<(2048 * 512) / 256, 256, 0, stream>>>(W_ih_d, W_hh_d, W_sum, 2048 * 512);

  // Regular launches: 256 blocks / 256 CUs at __launch_bounds__(256,1) are
  // always co-resident; barriers are custom bounded-spin atomics (no
  // grid.sync), so cooperative launch is unnecessary.
  k_encoder<<<dim3(256), dim3(256), 0, stream>>>(
      sh, W_ih_e, W_hh_e, b_ih_e, b_hh_e, enc_out, hT, c_buf, bar);
  k_decoder<<<dim3(256), dim3(256), 0, stream>>>(
      W_hh_d, W_sum, b_ih_d, b_hh_d, c_buf, Hd, hT, bar);

  // scores[b][s][t] = Hd[b][s][:] . enc_out[b][t][:]
  k_gemm<0><<<dim3(8, 1, 64), 256, 0, stream>>>(
      Hd, nullptr, enc_out, nullptr, scores, S_, T_, H_,
      (long)S_ * H_, (long)T_ * H_, (long)S_ * T_);
  // softmax over t (in place in d_out)
  k_softmax<<<B_ * S_, 256, 0, stream>>>(scores);
  // ctx[b][s][h] = aw[b][s][:] @ enc_out[b][:][h]
  k_gemm<1><<<dim3(4, 1, 64), 256, 0, stream>>>(
      scores, nullptr, enc_out, nullptr, ctx, S_, H_, T_,
      (long)S_ * T_, (long)T_ * H_, (long)S_ * H_);
  // attn_applied = [ctx, Hd] @ W_attn^T + b_attn
  k_gemm<2><<<dim3(4, 50, 1), 256, 0, stream>>>(
      ctx, Hd, W_attn, b_attn, attn, B_ * S_, H_, 2 * H_, 0, 0, 0);
  // logits = attn_applied @ W_fc^T + b_fc   (overwrites scores, now dead)
  k_gemm<3><<<dim3(8, 50, 1), 256, 0, stream>>>(
      attn, nullptr, W_fc, b_fc, logits, B_ * S_, V_, H_, 0, 0, 0);
}

// Round 9
// 23330.386 us; speedup vs baseline: 1.2628x; 1.2628x over previous
//
#include <hip/hip_runtime.h>
#include <math.h>

#define B_ 64
#define T_ 1000
#define IN_ 80
#define H_ 512
#define V_ 1000
#define S_ 100

// ---------------------------------------------------------------------------
// split-phase group barrier — ZERO cache-maintenance ops.
// R7 post-mortem: the old release-fetch_add (buffer_wbl2) + threadfence
// (buffer_inv) pair, per block per step, was ~64 full-L2 walks per XCD per
// step -> 25.8 us/step, VALUBusy 11%. Scheme: the shared data (hT) moves
// via fine-grained agent-scope RELAXED atomics (L1/L2-bypass, L3-coherent,
// placement-independent), so the barrier needs NO fences:
//   arrive: __syncthreads() (compiler emits s_waitcnt vmcnt(0) before
//           s_barrier -> all hT atomic stores are at L3) + relaxed fetch_add.
//   wait:   relaxed polls; data loads are sc-bypass so never stale.
// R8b: each counter on its own 256B line (was: all 8 in one 64B line ->
// every block's RMW + every poll serialized on a single L3 line).
// ---------------------------------------------------------------------------
__device__ __forceinline__ void bar_arrive(unsigned* ctr) {
  __syncthreads();  // drains vmcnt(0): hT atomic stores globally visible
  if (threadIdx.x == 0)
    __hip_atomic_fetch_add(ctr, 1u, __ATOMIC_RELAXED, __HIP_MEMORY_SCOPE_AGENT);
}
__device__ __forceinline__ void bar_wait(unsigned* ctr, unsigned target) {
  if (threadIdx.x == 0) {
    long guard = 0;
    while (__hip_atomic_load(ctr, __ATOMIC_RELAXED, __HIP_MEMORY_SCOPE_AGENT) < target) {
      __builtin_amdgcn_s_sleep(1);
      if (++guard > 50000) break;  // fast-fail: wrong-but-finite instead of hang
    }
  }
  __syncthreads();
}

__device__ __forceinline__ float sigm(float x) { return 1.f / (1.f + __expf(-x)); }

// ---------------------------------------------------------------------------
// sentinel: ws_size too small -> readable failure instead of memory fault
// ---------------------------------------------------------------------------
__global__ void k_sentinel(float* __restrict__ out, float required_mb) {
  if (threadIdx.x == 0 && blockIdx.x == 0) out[0] = required_mb;
}

// ---------------------------------------------------------------------------
// K0: transpose x[B][T][IN] -> xT[T][IN][B]
// ---------------------------------------------------------------------------
__global__ void k_transpose_x(const float* __restrict__ x, float* __restrict__ xT) {
  __shared__ float tile[64][81];
  const int t = blockIdx.x;
  for (int idx = threadIdx.x; idx < 64 * IN_; idx += 256) {
    const int b = idx / IN_, k = idx % IN_;
    tile[b][k] = x[((size_t)b * T_ + t) * IN_ + k];
  }
  __syncthreads();
  for (int idx = threadIdx.x; idx < IN_ * 64; idx += 256) {
    const int k = idx >> 6, b = idx & 63;
    xT[((size_t)t * IN_ + k) * 64 + b] = tile[b][k];
  }
}

// ---------------------------------------------------------------------------
// K0b: W_sum = W_ih_d + W_hh_d  (decoder steps >=1 have x input == h)
// ---------------------------------------------------------------------------
__global__ void k_wsum(const float* __restrict__ a, const float* __restrict__ b,
                       float* __restrict__ o, int n) {
  const int i = blockIdx.x * 256 + threadIdx.x;
  if (i < n) o[i] = a[i] + b[i];
}

// ---------------------------------------------------------------------------
// Encoder: persistent kernel, 1000 sequential LSTM steps.
// 256 blocks = 4 b-groups (16 batch rows) x 64 n-blocks (8 j-cols x 4 gates).
// XCD remap: ng = (bid&7)*8 + ((bid>>3)&7) -> per-XCD W working set 606 KB,
// L2-resident (no per-step L2 invalidates anywhere in the loop).
// hT[2][512][64] double-buffered; ALL hT traffic via fine-grained agent
// atomics (sc-bypass, L3-coherent) -> no fences, W/xT stay cached.
// ---------------------------------------------------------------------------
__launch_bounds__(256, 1)
__global__ void k_encoder(const float* __restrict__ xT,
                          const float* __restrict__ W_ih_e,   // [2048][80]
                          const float* __restrict__ W_hh_e,   // [2048][512]
                          const float* __restrict__ b_ih_e,
                          const float* __restrict__ b_hh_e,
                          float* __restrict__ enc_out,        // [B][T][H]
                          float* __restrict__ hT,             // [2][512][64]
                          float* __restrict__ c_buf,          // [B][H]
                          unsigned* __restrict__ bar) {
  const int tid = threadIdx.x;
  const int bid = blockIdx.x;
  const int gb  = bid >> 6;                          // b-group 0..3 (barrier group)
  const int ng  = (bid & 7) * 8 + ((bid >> 3) & 7);  // n-group 0..63, XCD-sliced
  const int bl  = tid & 15;          // local batch row 0..15
  const int rq  = tid >> 4;          // 0..15
  const int b_glob = gb * 16 + bl;
  const int jj  = rq & 7;
  const int gh  = rq >> 3;               // 0: gate i, 1: gate f
  const int j   = ng * 8 + jj;
  const int n1  = gh * 512 + j;          // i or f row
  const int n2  = n1 + 1024;             // g or o row

  unsigned* hTu = (unsigned*)hT;
  unsigned* mybar = bar + gb * 64;       // own 256B line per barrier group

  __shared__ float hx[16][596];   // [b][k]: 80 x-part + 512 h-part (pitch 596)
  __shared__ float gbuf[16][33];  // padded: conflict-free gate exchange

  const float bias1 = b_ih_e[n1] + b_hh_e[n1];
  const float bias2 = b_ih_e[n2] + b_hh_e[n2];
  const float4* Wx1 = (const float4*)(W_ih_e + (size_t)n1 * IN_);
  const float4* Wx2 = (const float4*)(W_ih_e + (size_t)n2 * IN_);
  const float4* Wh1 = (const float4*)(W_hh_e + (size_t)n1 * H_);
  const float4* Wh2 = (const float4*)(W_hh_e + (size_t)n2 * H_);

  float c = 0.f;
  unsigned wait_target = 0;

  // prologue: stage x-part for t=0 (320 float4 = 16 rows x 80 k)
  for (int idx = tid; idx < 320; idx += 256) {
    const int k = idx >> 2, bb4 = (idx & 3) * 4;
    const float4 v = *(const float4*)&xT[(size_t)0 * (IN_ * 64) + k * 64 + gb * 16 + bb4];
    hx[bb4 + 0][k] = v.x; hx[bb4 + 1][k] = v.y;
    hx[bb4 + 2][k] = v.z; hx[bb4 + 3][k] = v.w;
  }

  for (int t = 0; t < T_; ++t) {
    bar_wait(mybar, wait_target);      // h_t at L3 (t=0: trivial) + syncthreads
    const unsigned* hsrcu = hTu + (size_t)(t & 1) * H_ * 64;
    // stage h slice [16][512]: 32 fine-grained loads/thread (L3-coherent,
    // lanes 0..15 hit one 64B line -> coalesced at the request level)
    #pragma unroll
    for (int l = 0; l < 32; ++l) {
      const int idx = tid + l * 256;
      const int bb = idx & 15, k = idx >> 4;
      const unsigned u = __hip_atomic_load(&hsrcu[k * 64 + gb * 16 + bb],
                                           __ATOMIC_RELAXED, __HIP_MEMORY_SCOPE_AGENT);
      hx[bb][IN_ + k] = __uint_as_float(u);
    }
    __syncthreads();

    float acc1 = bias1, acc2 = bias2;
    const float4* hx4 = (const float4*)(&hx[bl][0]);
    #pragma unroll 10
    for (int i = 0; i < IN_ / 4; ++i) {
      const float4 h4 = hx4[i];
      const float4 w1 = Wx1[i], w2 = Wx2[i];
      acc1 = fmaf(h4.x, w1.x, acc1); acc1 = fmaf(h4.y, w1.y, acc1);
      acc1 = fmaf(h4.z, w1.z, acc1); acc1 = fmaf(h4.w, w1.w, acc1);
      acc2 = fmaf(h4.x, w2.x, acc2); acc2 = fmaf(h4.y, w2.y, acc2);
      acc2 = fmaf(h4.z, w2.z, acc2); acc2 = fmaf(h4.w, w2.w, acc2);
    }
    const float4* hh4 = (const float4*)(&hx[bl][IN_]);
    #pragma unroll 16
    for (int i = 0; i < H_ / 4; ++i) {
      const float4 h4 = hh4[i];
      const float4 w1 = Wh1[i], w2 = Wh2[i];
      acc1 = fmaf(h4.x, w1.x, acc1); acc1 = fmaf(h4.y, w1.y, acc1);
      acc1 = fmaf(h4.z, w1.z, acc1); acc1 = fmaf(h4.w, w1.w, acc1);
      acc2 = fmaf(h4.x, w2.x, acc2); acc2 = fmaf(h4.y, w2.y, acc2);
      acc2 = fmaf(h4.z, w2.z, acc2); acc2 = fmaf(h4.w, w2.w, acc2);
    }

    gbuf[bl][rq] = acc1;       // rq 0..7: gate i, 8..15: gate f
    __syncthreads();
    gbuf[bl][rq + 16] = acc2;  // 16..23: gate g, 24..31: gate o
    __syncthreads();

    float hval = 0.f;
    if (rq < 8) {
      const float gi = gbuf[bl][jj];
      const float gf = gbuf[bl][8 + jj];
      const float gg = gbuf[bl][16 + jj];
      const float go = gbuf[bl][24 + jj];
      c = sigm(gf) * c + sigm(gi) * tanhf(gg);
      hval = sigm(go) * tanhf(c);
      __hip_atomic_store(&hTu[(size_t)((t + 1) & 1) * H_ * 64 + j * 64 + b_glob],
                         __float_as_uint(hval),
                         __ATOMIC_RELAXED, __HIP_MEMORY_SCOPE_AGENT);
    }
    bar_arrive(mybar);                 // syncthreads (vmcnt drain) + relaxed bump
    wait_target += 64;

    // ---- overlap region: runs under other blocks' arrival latency ----
    if (rq < 8) enc_out[((size_t)b_glob * T_ + t) * H_ + j] = hval;
    if (t + 1 < T_) {                  // stage x-part for t+1 (hx free: compute done)
      for (int idx = tid; idx < 320; idx += 256) {
        const int k = idx >> 2, bb4 = (idx & 3) * 4;
        const float4 v =
            *(const float4*)&xT[(size_t)(t + 1) * (IN_ * 64) + k * 64 + gb * 16 + bb4];
        hx[bb4 + 0][k] = v.x; hx[bb4 + 1][k] = v.y;
        hx[bb4 + 2][k] = v.z; hx[bb4 + 3][k] = v.w;
      }
    }
  }
  if (rq < 8) c_buf[(size_t)b_glob * H_ + j] = c;
}

// ---------------------------------------------------------------------------
// Decoder LSTM: 100 sequential steps. dec_in == previous h (step 0: x = 0),
// so gates = h @ (W_ih_d + W_hh_d)^T + b   (step 0: h @ W_hh_d^T + b).
// Attention does NOT feed back -> done later as parallel GEMMs.
// Same fence-free fine-grained-hT scheme as encoder.
// ---------------------------------------------------------------------------
__launch_bounds__(256, 1)
__global__ void k_decoder(const float* __restrict__ W_hh_d,  // [2048][512]
                          const float* __restrict__ W_sum,   // [2048][512]
                          const float* __restrict__ b_ih_d,
                          const float* __restrict__ b_hh_d,
                          const float* __restrict__ c_in,    // [B][H]
                          float* __restrict__ Hd,            // [B][S][H]
                          float* __restrict__ hT,            // [2][512][64]
                          unsigned* __restrict__ bar) {
  const int tid = threadIdx.x;
  const int bid = blockIdx.x;
  const int gb  = bid >> 6;
  const int ng  = (bid & 7) * 8 + ((bid >> 3) & 7);
  const int bl  = tid & 15;
  const int rq  = tid >> 4;
  const int b_glob = gb * 16 + bl;
  const int jj  = rq & 7;
  const int gh  = rq >> 3;
  const int j   = ng * 8 + jj;
  const int n1  = gh * 512 + j;
  const int n2  = n1 + 1024;

  unsigned* hTu = (unsigned*)hT;
  unsigned* mybar = bar + (8 + gb) * 64;  // own 256B line per barrier group

  __shared__ float hb[16][516];
  __shared__ float gbuf[16][33];

  const float bias1 = b_ih_d[n1] + b_hh_d[n1];
  const float bias2 = b_ih_d[n2] + b_hh_d[n2];

  float c = (rq < 8) ? c_in[(size_t)b_glob * H_ + j] : 0.f;
  unsigned wait_target = 0;

  for (int s = 0; s < S_; ++s) {
    bar_wait(mybar, wait_target);
    const unsigned* hsrcu = hTu + (size_t)(s & 1) * H_ * 64;
    #pragma unroll
    for (int l = 0; l < 32; ++l) {
      const int idx = tid + l * 256;
      const int bb = idx & 15, k = idx >> 4;
      const unsigned u = __hip_atomic_load(&hsrcu[k * 64 + gb * 16 + bb],
                                           __ATOMIC_RELAXED, __HIP_MEMORY_SCOPE_AGENT);
      hb[bb][k] = __uint_as_float(u);
    }
    __syncthreads();

    const float* Wbase = (s == 0) ? W_hh_d : W_sum;
    const float4* W1 = (const float4*)(Wbase + (size_t)n1 * H_);
    const float4* W2 = (const float4*)(Wbase + (size_t)n2 * H_);
    float acc1 = bias1, acc2 = bias2;
    const float4* h4p = (const float4*)(&hb[bl][0]);
    #pragma unroll 16
    for (int i = 0; i < H_ / 4; ++i) {
      const float4 h4 = h4p[i];
      const float4 w1 = W1[i], w2 = W2[i];
      acc1 = fmaf(h4.x, w1.x, acc1); acc1 = fmaf(h4.y, w1.y, acc1);
      acc1 = fmaf(h4.z, w1.z, acc1); acc1 = fmaf(h4.w, w1.w, acc1);
      acc2 = fmaf(h4.x, w2.x, acc2); acc2 = fmaf(h4.y, w2.y, acc2);
      acc2 = fmaf(h4.z, w2.z, acc2); acc2 = fmaf(h4.w, w2.w, acc2);
    }

    gbuf[bl][rq] = acc1;
    __syncthreads();
    gbuf[bl][rq + 16] = acc2;
    __syncthreads();

    float hval = 0.f;
    if (rq < 8) {
      const float gi = gbuf[bl][jj];
      const float gf = gbuf[bl][8 + jj];
      const float gg = gbuf[bl][16 + jj];
      const float go = gbuf[bl][24 + jj];
      c = sigm(gf) * c + sigm(gi) * tanhf(gg);
      hval = sigm(go) * tanhf(c);
      __hip_atomic_store(&hTu[(size_t)((s + 1) & 1) * H_ * 64 + j * 64 + b_glob],
                         __float_as_uint(hval),
                         __ATOMIC_RELAXED, __HIP_MEMORY_SCOPE_AGENT);
    }
    bar_arrive(mybar);
    wait_target += 64;
    // overlap: Hd is not read inside the loop
    if (rq < 8) Hd[((size_t)b_glob * S_ + s) * H_ + j] = hval;
  }
}

// ---------------------------------------------------------------------------
// Tiled GEMM: C[M][N] = A[M][K] @ B (+bias). 128x128 tile, kc=16, 8x8 micro.
// MODE 0: B=[N][K] (NT), batched over z      -> scores
// MODE 1: B=[K][N] (NN), batched over z      -> ctx
// MODE 2: NT flat, A=concat(ctx,Hd), +bias   -> attn_applied
// MODE 3: NT flat, +bias                     -> logits
// ---------------------------------------------------------------------------
template <int MODE>
__launch_bounds__(256, 2)
__global__ void k_gemm(const float* __restrict__ A, const float* __restrict__ A2,
                       const float* __restrict__ Bm, const float* __restrict__ bias,
                       float* __restrict__ C, int M, int N, int K,
                       long sA, long sB, long sC) {
  constexpr bool NN = (MODE == 1);
  constexpr bool CONCAT = (MODE == 2);
  constexpr bool HASBIAS = (MODE >= 2);
  __shared__ float As[16][132];  // [k][m]
  __shared__ float Bs[16][132];  // [k][n]
  const int bz = blockIdx.z;
  const float* Ab = A + (long)bz * sA;
  const float* Bb = Bm + (long)bz * sB;
  float* Cb = C + (long)bz * sC;
  const int m0 = blockIdx.y * 128, n0 = blockIdx.x * 128;
  const int tid = threadIdx.x;
  const int tx = tid & 15, ty = tid >> 4;
  float acc[8][8] = {};

  for (int kc = 0; kc < K; kc += 16) {
    // A tile: 128m x 16k -> As[k][m]
    #pragma unroll
    for (int l = 0; l < 8; ++l) {
      const int idx = tid + l * 256;
      const int m = idx >> 4, k = idx & 15;
      const int mm = m0 + m, kk = kc + k;
      float v = 0.f;
      if (mm < M && kk < K) {
        if (CONCAT) v = (kk < H_) ? Ab[(long)mm * H_ + kk] : A2[(long)mm * H_ + (kk - H_)];
        else        v = Ab[(long)mm * K + kk];
      }
      As[k][m] = v;
    }
    // B tile: 128n x 16k -> Bs[k][n]
    #pragma unroll
    for (int l = 0; l < 8; ++l) {
      const int idx = tid + l * 256;
      int n, k;
      if (NN) { n = idx & 127; k = idx >> 7; }
      else    { k = idx & 15;  n = idx >> 4; }
      const int nn = n0 + n, kk = kc + k;
      float v = 0.f;
      if (nn < N && kk < K)
        v = NN ? Bb[(long)kk * N + nn] : Bb[(long)nn * K + kk];
      Bs[k][n] = v;
    }
    __syncthreads();

    #pragma unroll 8
    for (int k = 0; k < 16; ++k) {
      const float4 a0 = *(const float4*)&As[k][ty * 4];
      const float4 a1 = *(const float4*)&As[k][ty * 4 + 64];
      const float4 b0 = *(const float4*)&Bs[k][tx * 4];
      const float4 b1 = *(const float4*)&Bs[k][tx * 4 + 64];
      const float a[8] = {a0.x, a0.y, a0.z, a0.w, a1.x, a1.y, a1.z, a1.w};
      const float b[8] = {b0.x, b0.y, b0.z, b0.w, b1.x, b1.y, b1.z, b1.w};
      #pragma unroll
      for (int i = 0; i < 8; ++i)
        #pragma unroll
        for (int jy = 0; jy < 8; ++jy)
          acc[i][jy] = fmaf(a[i], b[jy], acc[i][jy]);
    }
    __syncthreads();
  }

  #pragma unroll
  for (int i = 0; i < 8; ++i) {
    const int m = m0 + ty * 4 + (i & 3) + (i >> 2) * 64;
    if (m >= M) continue;
    #pragma unroll
    for (int jy = 0; jy < 8; ++jy) {
      const int n = n0 + tx * 4 + (jy & 3) + (jy >> 2) * 64;
      if (n < N) {
        float v = acc[i][jy];
        if (HASBIAS) v += bias[n];
        Cb[(long)m * N + n] = v;
      }
    }
  }
}

// ---------------------------------------------------------------------------
// Softmax over T for each (b,s) row of scores[B][S][T], in place.
// Wave __shfl_xor reduce + 8-float LDS combine (2 syncthreads total).
// ---------------------------------------------------------------------------
__global__ void k_softmax(float* __restrict__ scores) {
  __shared__ float red[8];
  float* row = scores + (size_t)blockIdx.x * T_;
  const int tid = threadIdx.x;
  const int lane = tid & 63, wv = tid >> 6;
  float r[4];
  float mx = -1e30f;
  #pragma unroll
  for (int i = 0; i < 4; ++i) {
    const int idx = tid + i * 256;
    r[i] = (idx < T_) ? row[idx] : -1e30f;
    mx = fmaxf(mx, r[i]);
  }
  #pragma unroll
  for (int off = 32; off > 0; off >>= 1) mx = fmaxf(mx, __shfl_xor(mx, off, 64));
  if (lane == 0) red[wv] = mx;
  __syncthreads();
  mx = fmaxf(fmaxf(red[0], red[1]), fmaxf(red[2], red[3]));
  float sum = 0.f;
  #pragma unroll
  for (int i = 0; i < 4; ++i) {
    const int idx = tid + i * 256;
    r[i] = (idx < T_) ? __expf(r[i] - mx) : 0.f;
    sum += r[i];
  }
  #pragma unroll
  for (int off = 32; off > 0; off >>= 1) sum += __shfl_xor(sum, off, 64);
  if (lane == 0) red[4 + wv] = sum;
  __syncthreads();
  const float inv = 1.f / (red[4] + red[5] + red[6] + red[7]);
  #pragma unroll
  for (int i = 0; i < 4; ++i) {
    const int idx = tid + i * 256;
    if (idx < T_) row[idx] = r[i] * inv;
  }
}

// ---------------------------------------------------------------------------
// launcher
// ---------------------------------------------------------------------------
extern "C" void kernel_launch(void* const* d_in, const int* in_sizes, int n_in,
                              void* d_out, int out_size, void* d_ws, size_t ws_size,
                              hipStream_t stream) {
  const float* x      = (const float*)d_in[0];
  const float* W_ih_e = (const float*)d_in[1];
  const float* W_hh_e = (const float*)d_in[2];
  const float* b_ih_e = (const float*)d_in[3];
  const float* b_hh_e = (const float*)d_in[4];
  const float* W_ih_d = (const float*)d_in[5];
  const float* W_hh_d = (const float*)d_in[6];
  const float* b_ih_d = (const float*)d_in[7];
  const float* b_hh_d = (const float*)d_in[8];
  const float* W_attn = (const float*)d_in[9];
  const float* b_attn = (const float*)d_in[10];
  const float* W_fc   = (const float*)d_in[11];
  const float* b_fc   = (const float*)d_in[12];
  // d_in[13] = max_len (always 100, compile-time S_)

  // ---- workspace layout ----
  // bar        : 4096 B (12 counters, each on its own 256B line)
  // sh         : 5,120,000 fl  (xT [T][IN][64]; later reused for attn_applied)
  // enc_out    : 32,768,000 fl ([B][T][H])
  // hT         : 65,536 fl     ([2][512][64])
  // c_buf      : 32,768 fl     ([B][H])
  // Hd         : 3,276,800 fl  ([B][S][H])
  // ctx        : 3,276,800 fl  ([B][S][H])
  // W_sum      : 1,048,576 fl  ([2048][512])
  // scores     : aliased into d_out (exactly out_size = 6,400,000 floats)
  const size_t need_fl = 5120000ull + 32768000ull + 65536ull + 32768ull +
                         3276800ull + 3276800ull + 1048576ull;
  const size_t required = 4096ull + need_fl * 4ull;
  if (ws_size < required) {
    // readable failure: d_out[0] = required MB (instead of an OOB fault)
    k_sentinel<<<1, 64, 0, stream>>>((float*)d_out, (float)(required >> 20));
    return;
  }

  unsigned* bar  = (unsigned*)d_ws;
  float* sh      = (float*)((char*)d_ws + 4096);
  float* enc_out = sh + 5120000;
  float* hT      = enc_out + 32768000;
  float* c_buf   = hT + 65536;
  float* Hd      = c_buf + 32768;
  float* ctx     = Hd + 3276800;
  float* W_sum   = ctx + 3276800;
  float* scores  = (float*)d_out;   // [B][S][T] == out_size, dead before logits
  float* attn    = sh;              // xT dead once encoder finishes
  float* logits  = (float*)d_out;

  hipMemsetAsync(d_ws, 0, 4096, stream);                       // barrier counters
  hipMemsetAsync(hT, 0, 2 * H_ * 64 * sizeof(float), stream);  // h0 = 0

  k_transpose_x<<<T_, 256, 0, stream>>>(x, sh);
  k_wsum<<<(2048 * 512) / 256, 256, 0, stream>>>(W_ih_d, W_hh_d, W_sum, 2048 * 512);

  k_encoder<<<dim3(256), dim3(256), 0, stream>>>(
      sh, W_ih_e, W_hh_e, b_ih_e, b_hh_e, enc_out, hT, c_buf, bar);
  k_decoder<<<dim3(256), dim3(256), 0, stream>>>(
      W_hh_d, W_sum, b_ih_d, b_hh_d, c_buf, Hd, hT, bar);

  // scores[b][s][t] = Hd[b][s][:] . enc_out[b][t][:]
  k_gemm<0><<<dim3(8, 1, 64), 256, 0, stream>>>(
      Hd, nullptr, enc_out, nullptr, scores, S_, T_, H_,
      (long)S_ * H_, (long)T_ * H_, (long)S_ * T_);
  // softmax over t (in place in d_out)
  k_softmax<<<B_ * S_, 256, 0, stream>>>(scores);
  // ctx[b][s][h] = aw[b][s][:] @ enc_out[b][:][h]
  k_gemm<1><<<dim3(4, 1, 64), 256, 0, stream>>>(
      scores, nullptr, enc_out, nullptr, ctx, S_, H_, T_,
      (long)S_ * T_, (long)T_ * H_, (long)S_ * H_);
  // attn_applied = [ctx, Hd] @ W_attn^T + b_attn
  k_gemm<2><<<dim3(4, 50, 1), 256, 0, stream>>>(
      ctx, Hd, W_attn, b_attn, attn, B_ * S_, H_, 2 * H_, 0, 0, 0);
  // logits = attn_applied @ W_fc^T + b_fc   (overwrites scores, now dead)
  k_gemm<3><<<dim3(8, 50, 1), 256, 0, stream>>>(
      attn, nullptr, W_fc, b_fc, logits, B_ * S_, V_, H_, 0, 0, 0);
}

// Round 10
// 15204.553 us; speedup vs baseline: 1.9376x; 1.5344x over previous
//
#include <hip/hip_runtime.h>
#include <math.h>

#define B_ 64
#define T_ 1000
#define IN_ 80
#define H_ 512
#define V_ 1000
#define S_ 100

// ---------------------------------------------------------------------------
// Tree barrier (per b-group: 64 blocks = 8 sub-groups x 8).
// R9 post-mortem: flat 64-RMW counter + 64 pollers on one L3 line left
// VALUBusy at 14% (20.6 us/step). Tree: each block RMWs its sub-counter
// (8 RMWs/line, no pollers); the 8th arriver (fetch_add return == 8t+7)
// RMWs the root; 64 blocks poll only the root at s_sleep(2) cadence.
// All counters RELAXED agent-scope (serviced at L3, no L2 walks); each on
// its own 256B line. Ordering: producer's __syncthreads() before arrive
// drains vmcnt(0) -> hT stores are at the coherence point before the RMW;
// poll -> sub -> root chain is causally ordered by L3 line serialization.
// ---------------------------------------------------------------------------
__device__ __forceinline__ void tree_arrive(unsigned* subc, unsigned* root,
                                            unsigned step) {
  __syncthreads();  // drains vmcnt(0): hT stores globally visible
  if (threadIdx.x == 0) {
    const unsigned old = __hip_atomic_fetch_add(subc, 1u, __ATOMIC_RELAXED,
                                                __HIP_MEMORY_SCOPE_AGENT);
    if (old == step * 8u + 7u)  // last of this sub-group this step
      __hip_atomic_fetch_add(root, 1u, __ATOMIC_RELAXED,
                             __HIP_MEMORY_SCOPE_AGENT);
  }
}
__device__ __forceinline__ void tree_wait(unsigned* root, unsigned target) {
  if (threadIdx.x == 0) {
    long guard = 0;
    while (__hip_atomic_load(root, __ATOMIC_RELAXED,
                             __HIP_MEMORY_SCOPE_AGENT) < target) {
      __builtin_amdgcn_s_sleep(2);
      if (++guard > 50000) break;  // fast-fail: wrong-but-finite
    }
  }
  __syncthreads();
}

__device__ __forceinline__ float sigm(float x) { return 1.f / (1.f + __expf(-x)); }

// 8 x 16B L2-bypass loads (sc0 sc1 -> served at L3, coherent with the
// producers' agent-scope atomic hT stores), ONE waitcnt — the compiler
// cannot serialize this (R9 suspect: per-iteration atomic-load+wait).
#define LOAD8_SC(r0,r1,r2,r3,r4,r5,r6,r7, p0,p1,p2,p3,p4,p5,p6,p7)      \
  asm volatile(                                                          \
      "global_load_dwordx4 %0, %8, off sc0 sc1\n\t"                      \
      "global_load_dwordx4 %1, %9, off sc0 sc1\n\t"                      \
      "global_load_dwordx4 %2, %10, off sc0 sc1\n\t"                     \
      "global_load_dwordx4 %3, %11, off sc0 sc1\n\t"                     \
      "global_load_dwordx4 %4, %12, off sc0 sc1\n\t"                     \
      "global_load_dwordx4 %5, %13, off sc0 sc1\n\t"                     \
      "global_load_dwordx4 %6, %14, off sc0 sc1\n\t"                     \
      "global_load_dwordx4 %7, %15, off sc0 sc1\n\t"                     \
      "s_waitcnt vmcnt(0)"                                               \
      : "=&v"(r0), "=&v"(r1), "=&v"(r2), "=&v"(r3),                      \
        "=&v"(r4), "=&v"(r5), "=&v"(r6), "=&v"(r7)                       \
      : "v"(p0), "v"(p1), "v"(p2), "v"(p3),                              \
        "v"(p4), "v"(p5), "v"(p6), "v"(p7)                               \
      : "memory")

// ---------------------------------------------------------------------------
// sentinel: ws_size too small -> readable failure instead of memory fault
// ---------------------------------------------------------------------------
__global__ void k_sentinel(float* __restrict__ out, float required_mb) {
  if (threadIdx.x == 0 && blockIdx.x == 0) out[0] = required_mb;
}

// ---------------------------------------------------------------------------
// K0: transpose x[B][T][IN] -> xT[T][IN][B]
// ---------------------------------------------------------------------------
__global__ void k_transpose_x(const float* __restrict__ x, float* __restrict__ xT) {
  __shared__ float tile[64][81];
  const int t = blockIdx.x;
  for (int idx = threadIdx.x; idx < 64 * IN_; idx += 256) {
    const int b = idx / IN_, k = idx % IN_;
    tile[b][k] = x[((size_t)b * T_ + t) * IN_ + k];
  }
  __syncthreads();
  for (int idx = threadIdx.x; idx < IN_ * 64; idx += 256) {
    const int k = idx >> 6, b = idx & 63;
    xT[((size_t)t * IN_ + k) * 64 + b] = tile[b][k];
  }
}

// ---------------------------------------------------------------------------
// K0b: W_sum = W_ih_d + W_hh_d  (decoder steps >=1 have x input == h)
// ---------------------------------------------------------------------------
__global__ void k_wsum(const float* __restrict__ a, const float* __restrict__ b,
                       float* __restrict__ o, int n) {
  const int i = blockIdx.x * 256 + threadIdx.x;
  if (i < n) o[i] = a[i] + b[i];
}

// ---------------------------------------------------------------------------
// Encoder: persistent kernel, 1000 sequential LSTM steps.
// 256 blocks = 4 b-groups (16 batch rows) x 64 n-blocks (8 j-cols x 4 gates).
// XCD remap: ng = (bid&7)*8 + ((bid>>3)&7) -> per-XCD W slice 606 KB, L2-hot.
// hT[2][512][64] double-buffered; hT stores = agent atomics (at L3), hT loads
// = asm sc0/sc1 dwordx4 (at L3); no fences anywhere -> W/xT stay L2-cached.
// x-part of the dot product precomputed in the post-arrive overlap region.
// ---------------------------------------------------------------------------
__launch_bounds__(256, 1)
__global__ void k_encoder(const float* __restrict__ xT,
                          const float* __restrict__ W_ih_e,   // [2048][80]
                          const float* __restrict__ W_hh_e,   // [2048][512]
                          const float* __restrict__ b_ih_e,
                          const float* __restrict__ b_hh_e,
                          float* __restrict__ enc_out,        // [B][T][H]
                          float* __restrict__ hT,             // [2][512][64]
                          float* __restrict__ c_buf,          // [B][H]
                          unsigned* __restrict__ bar) {
  const int tid = threadIdx.x;
  const int bid = blockIdx.x;
  const int gb  = bid >> 6;                          // b-group (barrier group)
  const int sg  = (bid >> 3) & 7;                    // sub-barrier group 0..7
  const int ng  = (bid & 7) * 8 + sg;                // n-group, XCD-sliced
  const int bl  = tid & 15;
  const int rq  = tid >> 4;
  const int b_glob = gb * 16 + bl;
  const int jj  = rq & 7;
  const int gh  = rq >> 3;
  const int j   = ng * 8 + jj;
  const int n1  = gh * 512 + j;
  const int n2  = n1 + 1024;

  unsigned* hTu  = (unsigned*)hT;
  unsigned* subc = bar + (size_t)gb * 1024 + (size_t)sg * 64;
  unsigned* root = bar + (size_t)gb * 1024 + 512;

  __shared__ float hx[16][596];   // [b][k]: 80 x-part + 512 h-part
  __shared__ float gbuf[16][33];

  const float bias1 = b_ih_e[n1] + b_hh_e[n1];
  const float bias2 = b_ih_e[n2] + b_hh_e[n2];
  const float4* Wx1 = (const float4*)(W_ih_e + (size_t)n1 * IN_);
  const float4* Wx2 = (const float4*)(W_ih_e + (size_t)n2 * IN_);
  const float4* Wh1 = (const float4*)(W_hh_e + (size_t)n1 * H_);
  const float4* Wh2 = (const float4*)(W_hh_e + (size_t)n2 * H_);

  float c = 0.f;
  unsigned wait_target = 0;

  // prologue: stage x(0) + precompute x-part of the dot
  for (int idx = tid; idx < 320; idx += 256) {
    const int k = idx >> 2, bb4 = (idx & 3) * 4;
    const float4 v = *(const float4*)&xT[(size_t)0 * (IN_ * 64) + k * 64 + gb * 16 + bb4];
    hx[bb4 + 0][k] = v.x; hx[bb4 + 1][k] = v.y;
    hx[bb4 + 2][k] = v.z; hx[bb4 + 3][k] = v.w;
  }
  __syncthreads();
  float accx1 = bias1, accx2 = bias2;
  {
    const float4* hx4 = (const float4*)(&hx[bl][0]);
    #pragma unroll 10
    for (int i = 0; i < IN_ / 4; ++i) {
      const float4 h4 = hx4[i];
      const float4 w1 = Wx1[i], w2 = Wx2[i];
      accx1 = fmaf(h4.x, w1.x, accx1); accx1 = fmaf(h4.y, w1.y, accx1);
      accx1 = fmaf(h4.z, w1.z, accx1); accx1 = fmaf(h4.w, w1.w, accx1);
      accx2 = fmaf(h4.x, w2.x, accx2); accx2 = fmaf(h4.y, w2.y, accx2);
      accx2 = fmaf(h4.z, w2.z, accx2); accx2 = fmaf(h4.w, w2.w, accx2);
    }
  }

  for (int t = 0; t < T_; ++t) {
    tree_wait(root, wait_target);      // h_t at L3 (t=0: trivial)
    const float* hsrc = hT + (size_t)(t & 1) * H_ * 64;
    // ---- h-stage: 8x dwordx4 sc-loads, ONE waitcnt ----
    {
      float4 r0, r1, r2, r3, r4, r5, r6, r7;
      const float4* p0 = (const float4*)&hsrc[((tid + 0 * 256) >> 2) * 64 + gb * 16 + ((tid + 0 * 256) & 3) * 4];
      const float4* p1 = (const float4*)&hsrc[((tid + 1 * 256) >> 2) * 64 + gb * 16 + ((tid + 1 * 256) & 3) * 4];
      const float4* p2 = (const float4*)&hsrc[((tid + 2 * 256) >> 2) * 64 + gb * 16 + ((tid + 2 * 256) & 3) * 4];
      const float4* p3 = (const float4*)&hsrc[((tid + 3 * 256) >> 2) * 64 + gb * 16 + ((tid + 3 * 256) & 3) * 4];
      const float4* p4 = (const float4*)&hsrc[((tid + 4 * 256) >> 2) * 64 + gb * 16 + ((tid + 4 * 256) & 3) * 4];
      const float4* p5 = (const float4*)&hsrc[((tid + 5 * 256) >> 2) * 64 + gb * 16 + ((tid + 5 * 256) & 3) * 4];
      const float4* p6 = (const float4*)&hsrc[((tid + 6 * 256) >> 2) * 64 + gb * 16 + ((tid + 6 * 256) & 3) * 4];
      const float4* p7 = (const float4*)&hsrc[((tid + 7 * 256) >> 2) * 64 + gb * 16 + ((tid + 7 * 256) & 3) * 4];
      LOAD8_SC(r0, r1, r2, r3, r4, r5, r6, r7, p0, p1, p2, p3, p4, p5, p6, p7);
      __builtin_amdgcn_sched_barrier(0);  // rule #18: no hoisting past waitcnt
      #define PUT8(r, l) {                                                  \
        const int idx_ = tid + (l) * 256;                                   \
        const int k_ = idx_ >> 2, bb4_ = (idx_ & 3) * 4;                    \
        hx[bb4_ + 0][IN_ + k_] = r.x; hx[bb4_ + 1][IN_ + k_] = r.y;         \
        hx[bb4_ + 2][IN_ + k_] = r.z; hx[bb4_ + 3][IN_ + k_] = r.w; }
      PUT8(r0, 0) PUT8(r1, 1) PUT8(r2, 2) PUT8(r3, 3)
      PUT8(r4, 4) PUT8(r5, 5) PUT8(r6, 6) PUT8(r7, 7)
      #undef PUT8
    }
    __syncthreads();

    float acc1 = accx1, acc2 = accx2;  // x-part precomputed in overlap
    const float4* hh4 = (const float4*)(&hx[bl][IN_]);
    #pragma unroll 16
    for (int i = 0; i < H_ / 4; ++i) {
      const float4 h4 = hh4[i];
      const float4 w1 = Wh1[i], w2 = Wh2[i];
      acc1 = fmaf(h4.x, w1.x, acc1); acc1 = fmaf(h4.y, w1.y, acc1);
      acc1 = fmaf(h4.z, w1.z, acc1); acc1 = fmaf(h4.w, w1.w, acc1);
      acc2 = fmaf(h4.x, w2.x, acc2); acc2 = fmaf(h4.y, w2.y, acc2);
      acc2 = fmaf(h4.z, w2.z, acc2); acc2 = fmaf(h4.w, w2.w, acc2);
    }

    gbuf[bl][rq] = acc1;       // rq 0..7: gate i, 8..15: gate f
    __syncthreads();
    gbuf[bl][rq + 16] = acc2;  // 16..23: gate g, 24..31: gate o
    __syncthreads();

    float hval = 0.f;
    if (rq < 8) {
      const float gi = gbuf[bl][jj];
      const float gf = gbuf[bl][8 + jj];
      const float gg = gbuf[bl][16 + jj];
      const float go = gbuf[bl][24 + jj];
      c = sigm(gf) * c + sigm(gi) * tanhf(gg);
      hval = sigm(go) * tanhf(c);
      __hip_atomic_store(&hTu[(size_t)((t + 1) & 1) * H_ * 64 + j * 64 + b_glob],
                         __float_as_uint(hval),
                         __ATOMIC_RELAXED, __HIP_MEMORY_SCOPE_AGENT);
    }
    tree_arrive(subc, root, (unsigned)t);
    wait_target += 8;

    // ---- overlap region: under other blocks' arrival latency ----
    if (rq < 8) enc_out[((size_t)b_glob * T_ + t) * H_ + j] = hval;
    if (t + 1 < T_) {
      for (int idx = tid; idx < 320; idx += 256) {
        const int k = idx >> 2, bb4 = (idx & 3) * 4;
        const float4 v =
            *(const float4*)&xT[(size_t)(t + 1) * (IN_ * 64) + k * 64 + gb * 16 + bb4];
        hx[bb4 + 0][k] = v.x; hx[bb4 + 1][k] = v.y;
        hx[bb4 + 2][k] = v.z; hx[bb4 + 3][k] = v.w;
      }
      __syncthreads();
      accx1 = bias1; accx2 = bias2;
      const float4* hx4 = (const float4*)(&hx[bl][0]);
      #pragma unroll 10
      for (int i = 0; i < IN_ / 4; ++i) {
        const float4 h4 = hx4[i];
        const float4 w1 = Wx1[i], w2 = Wx2[i];
        accx1 = fmaf(h4.x, w1.x, accx1); accx1 = fmaf(h4.y, w1.y, accx1);
        accx1 = fmaf(h4.z, w1.z, accx1); accx1 = fmaf(h4.w, w1.w, accx1);
        accx2 = fmaf(h4.x, w2.x, accx2); accx2 = fmaf(h4.y, w2.y, accx2);
        accx2 = fmaf(h4.z, w2.z, accx2); accx2 = fmaf(h4.w, w2.w, accx2);
      }
    }
  }
  if (rq < 8) c_buf[(size_t)b_glob * H_ + j] = c;
}

// ---------------------------------------------------------------------------
// Decoder LSTM: 100 sequential steps. dec_in == previous h (step 0: x = 0),
// so gates = h @ (W_ih_d + W_hh_d)^T + b   (step 0: h @ W_hh_d^T + b).
// Attention does NOT feed back -> done later as parallel GEMMs.
// Same asm sc-load staging + tree barrier as encoder.
// ---------------------------------------------------------------------------
__launch_bounds__(256, 1)
__global__ void k_decoder(const float* __restrict__ W_hh_d,  // [2048][512]
                          const float* __restrict__ W_sum,   // [2048][512]
                          const float* __restrict__ b_ih_d,
                          const float* __restrict__ b_hh_d,
                          const float* __restrict__ c_in,    // [B][H]
                          float* __restrict__ Hd,            // [B][S][H]
                          float* __restrict__ hT,            // [2][512][64]
                          unsigned* __restrict__ bar) {
  const int tid = threadIdx.x;
  const int bid = blockIdx.x;
  const int gb  = bid >> 6;
  const int sg  = (bid >> 3) & 7;
  const int ng  = (bid & 7) * 8 + sg;
  const int bl  = tid & 15;
  const int rq  = tid >> 4;
  const int b_glob = gb * 16 + bl;
  const int jj  = rq & 7;
  const int gh  = rq >> 3;
  const int j   = ng * 8 + jj;
  const int n1  = gh * 512 + j;
  const int n2  = n1 + 1024;

  unsigned* hTu  = (unsigned*)hT;
  unsigned* subc = bar + (size_t)(4 + gb) * 1024 + (size_t)sg * 64;
  unsigned* root = bar + (size_t)(4 + gb) * 1024 + 512;

  __shared__ float hb[16][516];
  __shared__ float gbuf[16][33];

  const float bias1 = b_ih_d[n1] + b_hh_d[n1];
  const float bias2 = b_ih_d[n2] + b_hh_d[n2];

  float c = (rq < 8) ? c_in[(size_t)b_glob * H_ + j] : 0.f;
  unsigned wait_target = 0;

  for (int s = 0; s < S_; ++s) {
    tree_wait(root, wait_target);
    const float* hsrc = hT + (size_t)(s & 1) * H_ * 64;
    {
      float4 r0, r1, r2, r3, r4, r5, r6, r7;
      const float4* p0 = (const float4*)&hsrc[((tid + 0 * 256) >> 2) * 64 + gb * 16 + ((tid + 0 * 256) & 3) * 4];
      const float4* p1 = (const float4*)&hsrc[((tid + 1 * 256) >> 2) * 64 + gb * 16 + ((tid + 1 * 256) & 3) * 4];
      const float4* p2 = (const float4*)&hsrc[((tid + 2 * 256) >> 2) * 64 + gb * 16 + ((tid + 2 * 256) & 3) * 4];
      const float4* p3 = (const float4*)&hsrc[((tid + 3 * 256) >> 2) * 64 + gb * 16 + ((tid + 3 * 256) & 3) * 4];
      const float4* p4 = (const float4*)&hsrc[((tid + 4 * 256) >> 2) * 64 + gb * 16 + ((tid + 4 * 256) & 3) * 4];
      const float4* p5 = (const float4*)&hsrc[((tid + 5 * 256) >> 2) * 64 + gb * 16 + ((tid + 5 * 256) & 3) * 4];
      const float4* p6 = (const float4*)&hsrc[((tid + 6 * 256) >> 2) * 64 + gb * 16 + ((tid + 6 * 256) & 3) * 4];
      const float4* p7 = (const float4*)&hsrc[((tid + 7 * 256) >> 2) * 64 + gb * 16 + ((tid + 7 * 256) & 3) * 4];
      LOAD8_SC(r0, r1, r2, r3, r4, r5, r6, r7, p0, p1, p2, p3, p4, p5, p6, p7);
      __builtin_amdgcn_sched_barrier(0);
      #define PUTD(r, l) {                                                  \
        const int idx_ = tid + (l) * 256;                                   \
        const int k_ = idx_ >> 2, bb4_ = (idx_ & 3) * 4;                    \
        hb[bb4_ + 0][k_] = r.x; hb[bb4_ + 1][k_] = r.y;                     \
        hb[bb4_ + 2][k_] = r.z; hb[bb4_ + 3][k_] = r.w; }
      PUTD(r0, 0) PUTD(r1, 1) PUTD(r2, 2) PUTD(r3, 3)
      PUTD(r4, 4) PUTD(r5, 5) PUTD(r6, 6) PUTD(r7, 7)
      #undef PUTD
    }
    __syncthreads();

    const float* Wbase = (s == 0) ? W_hh_d : W_sum;
    const float4* W1 = (const float4*)(Wbase + (size_t)n1 * H_);
    const float4* W2 = (const float4*)(Wbase + (size_t)n2 * H_);
    float acc1 = bias1, acc2 = bias2;
    const float4* h4p = (const float4*)(&hb[bl][0]);
    #pragma unroll 16
    for (int i = 0; i < H_ / 4; ++i) {
      const float4 h4 = h4p[i];
      const float4 w1 = W1[i], w2 = W2[i];
      acc1 = fmaf(h4.x, w1.x, acc1); acc1 = fmaf(h4.y, w1.y, acc1);
      acc1 = fmaf(h4.z, w1.z, acc1); acc1 = fmaf(h4.w, w1.w, acc1);
      acc2 = fmaf(h4.x, w2.x, acc2); acc2 = fmaf(h4.y, w2.y, acc2);
      acc2 = fmaf(h4.z, w2.z, acc2); acc2 = fmaf(h4.w, w2.w, acc2);
    }

    gbuf[bl][rq] = acc1;
    __syncthreads();
    gbuf[bl][rq + 16] = acc2;
    __syncthreads();

    float hval = 0.f;
    if (rq < 8) {
      const float gi = gbuf[bl][jj];
      const float gf = gbuf[bl][8 + jj];
      const float gg = gbuf[bl][16 + jj];
      const float go = gbuf[bl][24 + jj];
      c = sigm(gf) * c + sigm(gi) * tanhf(gg);
      hval = sigm(go) * tanhf(c);
      __hip_atomic_store(&hTu[(size_t)((s + 1) & 1) * H_ * 64 + j * 64 + b_glob],
                         __float_as_uint(hval),
                         __ATOMIC_RELAXED, __HIP_MEMORY_SCOPE_AGENT);
    }
    tree_arrive(subc, root, (unsigned)s);
    wait_target += 8;
    if (rq < 8) Hd[((size_t)b_glob * S_ + s) * H_ + j] = hval;
  }
}

// ---------------------------------------------------------------------------
// Tiled GEMM: C[M][N] = A[M][K] @ B (+bias). 128x128 tile, kc=16, 8x8 micro.
// ---------------------------------------------------------------------------
template <int MODE>
__launch_bounds__(256, 2)
__global__ void k_gemm(const float* __restrict__ A, const float* __restrict__ A2,
                       const float* __restrict__ Bm, const float* __restrict__ bias,
                       float* __restrict__ C, int M, int N, int K,
                       long sA, long sB, long sC) {
  constexpr bool NN = (MODE == 1);
  constexpr bool CONCAT = (MODE == 2);
  constexpr bool HASBIAS = (MODE >= 2);
  __shared__ float As[16][132];  // [k][m]
  __shared__ float Bs[16][132];  // [k][n]
  const int bz = blockIdx.z;
  const float* Ab = A + (long)bz * sA;
  const float* Bb = Bm + (long)bz * sB;
  float* Cb = C + (long)bz * sC;
  const int m0 = blockIdx.y * 128, n0 = blockIdx.x * 128;
  const int tid = threadIdx.x;
  const int tx = tid & 15, ty = tid >> 4;
  float acc[8][8] = {};

  for (int kc = 0; kc < K; kc += 16) {
    #pragma unroll
    for (int l = 0; l < 8; ++l) {
      const int idx = tid + l * 256;
      const int m = idx >> 4, k = idx & 15;
      const int mm = m0 + m, kk = kc + k;
      float v = 0.f;
      if (mm < M && kk < K) {
        if (CONCAT) v = (kk < H_) ? Ab[(long)mm * H_ + kk] : A2[(long)mm * H_ + (kk - H_)];
        else        v = Ab[(long)mm * K + kk];
      }
      As[k][m] = v;
    }
    #pragma unroll
    for (int l = 0; l < 8; ++l) {
      const int idx = tid + l * 256;
      int n, k;
      if (NN) { n = idx & 127; k = idx >> 7; }
      else    { k = idx & 15;  n = idx >> 4; }
      const int nn = n0 + n, kk = kc + k;
      float v = 0.f;
      if (nn < N && kk < K)
        v = NN ? Bb[(long)kk * N + nn] : Bb[(long)nn * K + kk];
      Bs[k][n] = v;
    }
    __syncthreads();

    #pragma unroll 8
    for (int k = 0; k < 16; ++k) {
      const float4 a0 = *(const float4*)&As[k][ty * 4];
      const float4 a1 = *(const float4*)&As[k][ty * 4 + 64];
      const float4 b0 = *(const float4*)&Bs[k][tx * 4];
      const float4 b1 = *(const float4*)&Bs[k][tx * 4 + 64];
      const float a[8] = {a0.x, a0.y, a0.z, a0.w, a1.x, a1.y, a1.z, a1.w};
      const float b[8] = {b0.x, b0.y, b0.z, b0.w, b1.x, b1.y, b1.z, b1.w};
      #pragma unroll
      for (int i = 0; i < 8; ++i)
        #pragma unroll
        for (int jy = 0; jy < 8; ++jy)
          acc[i][jy] = fmaf(a[i], b[jy], acc[i][jy]);
    }
    __syncthreads();
  }

  #pragma unroll
  for (int i = 0; i < 8; ++i) {
    const int m = m0 + ty * 4 + (i & 3) + (i >> 2) * 64;
    if (m >= M) continue;
    #pragma unroll
    for (int jy = 0; jy < 8; ++jy) {
      const int n = n0 + tx * 4 + (jy & 3) + (jy >> 2) * 64;
      if (n < N) {
        float v = acc[i][jy];
        if (HASBIAS) v += bias[n];
        Cb[(long)m * N + n] = v;
      }
    }
  }
}

// ---------------------------------------------------------------------------
// Softmax over T for each (b,s) row of scores[B][S][T], in place.
// ---------------------------------------------------------------------------
__global__ void k_softmax(float* __restrict__ scores) {
  __shared__ float red[8];
  float* row = scores + (size_t)blockIdx.x * T_;
  const int tid = threadIdx.x;
  const int lane = tid & 63, wv = tid >> 6;
  float r[4];
  float mx = -1e30f;
  #pragma unroll
  for (int i = 0; i < 4; ++i) {
    const int idx = tid + i * 256;
    r[i] = (idx < T_) ? row[idx] : -1e30f;
    mx = fmaxf(mx, r[i]);
  }
  #pragma unroll
  for (int off = 32; off > 0; off >>= 1) mx = fmaxf(mx, __shfl_xor(mx, off, 64));
  if (lane == 0) red[wv] = mx;
  __syncthreads();
  mx = fmaxf(fmaxf(red[0], red[1]), fmaxf(red[2], red[3]));
  float sum = 0.f;
  #pragma unroll
  for (int i = 0; i < 4; ++i) {
    const int idx = tid + i * 256;
    r[i] = (idx < T_) ? __expf(r[i] - mx) : 0.f;
    sum += r[i];
  }
  #pragma unroll
  for (int off = 32; off > 0; off >>= 1) sum += __shfl_xor(sum, off, 64);
  if (lane == 0) red[4 + wv] = sum;
  __syncthreads();
  const float inv = 1.f / (red[4] + red[5] + red[6] + red[7]);
  #pragma unroll
  for (int i = 0; i < 4; ++i) {
    const int idx = tid + i * 256;
    if (idx < T_) row[idx] = r[i] * inv;
  }
}

// ---------------------------------------------------------------------------
// launcher
// ---------------------------------------------------------------------------
extern "C" void kernel_launch(void* const* d_in, const int* in_sizes, int n_in,
                              void* d_out, int out_size, void* d_ws, size_t ws_size,
                              hipStream_t stream) {
  const float* x      = (const float*)d_in[0];
  const float* W_ih_e = (const float*)d_in[1];
  const float* W_hh_e = (const float*)d_in[2];
  const float* b_ih_e = (const float*)d_in[3];
  const float* b_hh_e = (const float*)d_in[4];
  const float* W_ih_d = (const float*)d_in[5];
  const float* W_hh_d = (const float*)d_in[6];
  const float* b_ih_d = (const float*)d_in[7];
  const float* b_hh_d = (const float*)d_in[8];
  const float* W_attn = (const float*)d_in[9];
  const float* b_attn = (const float*)d_in[10];
  const float* W_fc   = (const float*)d_in[11];
  const float* b_fc   = (const float*)d_in[12];
  // d_in[13] = max_len (always 100, compile-time S_)

  // ---- workspace layout ----
  // bar  : 32768 B (8 groups x 4KB: 8 sub-counters + root, each on 256B line)
  // sh   : 5,120,000 fl (xT; later attn_applied)  | enc_out : 32,768,000 fl
  // hT   : 65,536 fl | c_buf : 32,768 fl | Hd, ctx : 3,276,800 fl each
  // W_sum: 1,048,576 fl | scores aliased into d_out
  const size_t need_fl = 5120000ull + 32768000ull + 65536ull + 32768ull +
                         3276800ull + 3276800ull + 1048576ull;
  const size_t required = 32768ull + need_fl * 4ull;
  if (ws_size < required) {
    k_sentinel<<<1, 64, 0, stream>>>((float*)d_out, (float)(required >> 20));
    return;
  }

  unsigned* bar  = (unsigned*)d_ws;
  float* sh      = (float*)((char*)d_ws + 32768);
  float* enc_out = sh + 5120000;
  float* hT      = enc_out + 32768000;
  float* c_buf   = hT + 65536;
  float* Hd      = c_buf + 32768;
  float* ctx     = Hd + 3276800;
  float* W_sum   = ctx + 3276800;
  float* scores  = (float*)d_out;   // dead before logits overwrite
  float* attn    = sh;              // xT dead once encoder finishes
  float* logits  = (float*)d_out;

  hipMemsetAsync(d_ws, 0, 32768, stream);                      // barrier counters
  hipMemsetAsync(hT, 0, 2 * H_ * 64 * sizeof(float), stream);  // h0 = 0

  k_transpose_x<<<T_, 256, 0, stream>>>(x, sh);
  k_wsum<<<(2048 * 512) / 256, 256, 0, stream>>>(W_ih_d, W_hh_d, W_sum, 2048 * 512);

  k_encoder<<<dim3(256), dim3(256), 0, stream>>>(
      sh, W_ih_e, W_hh_e, b_ih_e, b_hh_e, enc_out, hT, c_buf, bar);
  k_decoder<<<dim3(256), dim3(256), 0, stream>>>(
      W_hh_d, W_sum, b_ih_d, b_hh_d, c_buf, Hd, hT, bar);

  k_gemm<0><<<dim3(8, 1, 64), 256, 0, stream>>>(
      Hd, nullptr, enc_out, nullptr, scores, S_, T_, H_,
      (long)S_ * H_, (long)T_ * H_, (long)S_ * T_);
  k_softmax<<<B_ * S_, 256, 0, stream>>>(scores);
  k_gemm<1><<<dim3(4, 1, 64), 256, 0, stream>>>(
      scores, nullptr, enc_out, nullptr, ctx, S_, H_, T_,
      (long)S_ * T_, (long)T_ * H_, (long)S_ * H_);
  k_gemm<2><<<dim3(4, 50, 1), 256, 0, stream>>>(
      ctx, Hd, W_attn, b_attn, attn, B_ * S_, H_, 2 * H_, 0, 0, 0);
  k_gemm<3><<<dim3(8, 50, 1), 256, 0, stream>>>(
      attn, nullptr, W_fc, b_fc, logits, B_ * S_, V_, H_, 0, 0, 0);
}